// Round 5
// baseline (238.082 us; speedup 1.0000x reference)
//
#include <hip/hip_runtime.h>
#include <hip/hip_bf16.h>
#include <stdint.h>

// Problem: B=2, S=4096, D=512, H=8, hd=64. fp32 in/out, bf16 MFMA internally.
//
// ws layout (42 MB total):
//   [0,   8MB)  Xb    bf16 [8192,512]       input cast
//   [8,  10MB)  Wqt/Wkt/Wvt/Wot bf16 [512,512] each (transposed [N,K]; QKV contiguous)
//   [10, 18MB)  Qb    bf16 [B,H,S,64]  (pre-scaled by 0.125*log2e)
//   [18, 26MB)  Kb    bf16 [B,H,S,64]
//   [26, 34MB)  Vtb   bf16 [B,H,64,S]  (transposed for PV A-operand)
//   [34, 42MB)  Atb   bf16 [B,S,512]   attention output (pre-Wo)

typedef __bf16 bf16x8 __attribute__((ext_vector_type(8)));
typedef float f32x4 __attribute__((ext_vector_type(4)));

using as1_void = __attribute__((address_space(1))) void;
using as3_void = __attribute__((address_space(3))) void;

__device__ __forceinline__ void gload16(const void* g, void* l) {
    __builtin_amdgcn_global_load_lds((const as1_void*)g, (as3_void*)l, 16, 0, 0);
}

__device__ __forceinline__ f32x4 mfma16(bf16x8 a, bf16x8 b, f32x4 c) {
    return __builtin_amdgcn_mfma_f32_16x16x32_bf16(a, b, c, 0, 0, 0);
}

__device__ __forceinline__ uint32_t pkbf(float a, float b) {
    union { __hip_bfloat16 h[2]; uint32_t u; } r;
    r.h[0] = __float2bfloat16(a);   // low 16 = even element
    r.h[1] = __float2bfloat16(b);
    return r.u;
}

// ---------------------------------------------------------------- converts
__global__ void cvt_x(const float* __restrict__ in, __hip_bfloat16* __restrict__ out, int n) {
    int i = (blockIdx.x * 256 + threadIdx.x) * 4;
    if (i >= n) return;
    float4 v = *reinterpret_cast<const float4*>(in + i);
    union { __hip_bfloat16 h[4]; uint2 u; } r;
    r.h[0] = __float2bfloat16(v.x);
    r.h[1] = __float2bfloat16(v.y);
    r.h[2] = __float2bfloat16(v.z);
    r.h[3] = __float2bfloat16(v.w);
    *reinterpret_cast<uint2*>(out + i) = r.u;
}

// W [512,512] row-major [k][n] fp32  ->  Wt [n][k] bf16
__global__ void cvt_wt(const float* __restrict__ w0, const float* __restrict__ w1,
                       const float* __restrict__ w2, const float* __restrict__ w3,
                       __hip_bfloat16* __restrict__ o0, __hip_bfloat16* __restrict__ o1,
                       __hip_bfloat16* __restrict__ o2, __hip_bfloat16* __restrict__ o3) {
    const float* W; __hip_bfloat16* O;
    switch (blockIdx.z) {
        case 0: W = w0; O = o0; break;
        case 1: W = w1; O = o1; break;
        case 2: W = w2; O = o2; break;
        default: W = w3; O = o3; break;
    }
    __shared__ float t[32][33];
    int n0 = blockIdx.x * 32, k0 = blockIdx.y * 32;
    int tx = threadIdx.x, ty = threadIdx.y;
    for (int j = 0; j < 4; ++j)
        t[ty + 8 * j][tx] = W[(size_t)(k0 + ty + 8 * j) * 512 + n0 + tx];
    __syncthreads();
    for (int j = 0; j < 4; ++j)
        O[(size_t)(n0 + ty + 8 * j) * 512 + k0 + tx] = __float2bfloat16(t[tx][ty + 8 * j]);
}

// ---------------------------------------------------------------- fused QKV GEMM
__global__ __launch_bounds__(256, 2) void gemm_qkv(
    const __hip_bfloat16* __restrict__ A, const __hip_bfloat16* __restrict__ Bt,
    const float* __restrict__ bq, const float* __restrict__ bk, const float* __restrict__ bv,
    __hip_bfloat16* __restrict__ Qb, __hip_bfloat16* __restrict__ Kb,
    __hip_bfloat16* __restrict__ Vtb, float qs)
{
    const int K = 512;
    __shared__ __hip_bfloat16 Abuf[128 * 32];
    __shared__ __hip_bfloat16 Bbuf[128 * 32];
    const int tid = threadIdx.x, w = tid >> 6, lane = tid & 63;
    const int col = lane & 15, quad = lane >> 4;
    const int wr = w >> 1, wc = w & 1;
    const int tileN = blockIdx.x * 128, tileM = blockIdx.y * 128;

    f32x4 acc[4][4] = {};

    for (int k0 = 0; k0 < K; k0 += 32) {
        for (int i = 0; i < 2; ++i) {
            int g = w * 2 + i;
            int chunk = g * 64 + lane;
            int row = chunk >> 2, c8 = chunk & 3;
            gload16(A + (size_t)(tileM + row) * K + k0 + c8 * 8, Abuf + g * 512);
            gload16(Bt + (size_t)(tileN + row) * K + k0 + c8 * 8, Bbuf + g * 512);
        }
        __syncthreads();
        bf16x8 af[4], bfr[4];
        for (int mt = 0; mt < 4; ++mt)
            af[mt] = *reinterpret_cast<const bf16x8*>(Abuf + (wr * 64 + mt * 16 + col) * 32 + quad * 8);
        for (int nt = 0; nt < 4; ++nt)
            bfr[nt] = *reinterpret_cast<const bf16x8*>(Bbuf + (wc * 64 + nt * 16 + col) * 32 + quad * 8);
        for (int mt = 0; mt < 4; ++mt)
            for (int nt = 0; nt < 4; ++nt)
                acc[mt][nt] = mfma16(af[mt], bfr[nt], acc[mt][nt]);
        __syncthreads();
    }

    const int seg = (tileN + wc * 64) >> 9;   // wave-uniform
    const float* bias = (seg == 0) ? bq : (seg == 1) ? bk : bv;
    const float scale = (seg == 0) ? qs : 1.0f;
    __hip_bfloat16* outp = (seg == 0) ? Qb : (seg == 1) ? Kb : Vtb;

    for (int mt = 0; mt < 4; ++mt) {
        for (int nt = 0; nt < 4; ++nt) {
            int n = tileN + wc * 64 + nt * 16 + col;
            int nn = n & 511, h = nn >> 6, d = nn & 63;
            float bn = bias[nn];
            for (int r = 0; r < 4; ++r) {
                int m = tileM + wr * 64 + mt * 16 + quad * 4 + r;
                int b = m >> 12, s = m & 4095;
                float v = (acc[mt][nt][r] + bn) * scale;
                size_t off;
                if (seg < 2) off = (((size_t)(b * 8 + h) * 4096 + s) << 6) + d;
                else         off = (((size_t)(b * 8 + h) * 64 + d) << 12) + s;
                outp[off] = __float2bfloat16(v);
            }
        }
    }
}

// ---------------------------------------------------------------- final GEMM (Wo)
// 128(M) x 64(N) tiles -> 512 blocks = 2 blocks/CU (was 256 = 1/CU).
__global__ __launch_bounds__(256, 2) void gemm_out(
    const __hip_bfloat16* __restrict__ A, const __hip_bfloat16* __restrict__ Bt,
    const float* __restrict__ bias, float* __restrict__ out)
{
    const int N = 512, K = 512;
    __shared__ __hip_bfloat16 Abuf[128 * 32];
    __shared__ __hip_bfloat16 Bbuf[64 * 32];
    const int tid = threadIdx.x, w = tid >> 6, lane = tid & 63;
    const int col = lane & 15, quad = lane >> 4;
    const int tileN = blockIdx.x * 64, tileM = blockIdx.y * 128;

    f32x4 acc[2][4] = {};

    for (int k0 = 0; k0 < K; k0 += 32) {
        for (int i = 0; i < 2; ++i) {
            int g = w * 2 + i;
            int chunk = g * 64 + lane;
            int row = chunk >> 2, c8 = chunk & 3;
            gload16(A + (size_t)(tileM + row) * K + k0 + c8 * 8, Abuf + g * 512);
        }
        {
            int row = tid >> 2, c8 = tid & 3;
            gload16(Bt + (size_t)(tileN + row) * K + k0 + c8 * 8, Bbuf + tid * 8);
        }
        __syncthreads();
        bf16x8 af[2], bfr[4];
        for (int mt = 0; mt < 2; ++mt)
            af[mt] = *reinterpret_cast<const bf16x8*>(Abuf + (w * 32 + mt * 16 + col) * 32 + quad * 8);
        for (int nt = 0; nt < 4; ++nt)
            bfr[nt] = *reinterpret_cast<const bf16x8*>(Bbuf + (nt * 16 + col) * 32 + quad * 8);
        for (int mt = 0; mt < 2; ++mt)
            for (int nt = 0; nt < 4; ++nt)
                acc[mt][nt] = mfma16(af[mt], bfr[nt], acc[mt][nt]);
        __syncthreads();
    }

    for (int mt = 0; mt < 2; ++mt) {
        for (int nt = 0; nt < 4; ++nt) {
            int n = tileN + nt * 16 + col;
            float bn = bias[n];
            for (int r = 0; r < 4; ++r) {
                int m = tileM + w * 32 + mt * 16 + quad * 4 + r;
                out[(size_t)m * N + n] = acc[mt][nt][r] + bn;
            }
        }
    }
}

// ---------------------------------------------------------------- flash attention (v5)
// 512-thread blocks, 8 waves = 2 key-groups x 4 waves. Group g handles keys
// [g*2048, g*2048+2048) for the SAME 128 q rows -> grid still 512 blocks but
// 2 blocks/CU = 16 waves/CU = 4 waves/SIMD (was 2): TLP replaces the dropped
// intra-wave QK pipeline (register budget must stay <=128 for 16 waves/CU).
// Fixed-max softmax => partial (O, l) are directly ADDITIVE: group 1 dumps
// fp32 partials into the dead K-buffer LDS at the end; group 0 adds,
// normalizes, stores. TB is per-wave 2 KB, reused qh=0 then qh=1 (halves LDS).
// LDS: K 32K + V 32K + TB 16K = 80 KB -> exactly 2 blocks/CU.
__global__ __launch_bounds__(512, 4) void flash(
    const __hip_bfloat16* __restrict__ Q,   // [B*H, 4096, 64] (pre-scaled)
    const __hip_bfloat16* __restrict__ Kq,  // [B*H, 4096, 64]
    const __hip_bfloat16* __restrict__ Vt,  // [B*H, 64, 4096]
    __hip_bfloat16* __restrict__ attnb)     // [B, 4096, 512]
{
    __shared__ __hip_bfloat16 KT[2][2][4096];  // [group][parity] 32 KB
    __shared__ __hip_bfloat16 VB[2][2][4096];  // 32 KB
    __shared__ uint32_t TB[8][512];            // 16 KB per-wave P^T staging (one qh at a time)

    const int bh = blockIdx.y, b = bh >> 3, h = bh & 7;
    const int tid = threadIdx.x, w = tid >> 6, lane = tid & 63;
    const int g = w >> 2, wg = w & 3;
    const int col = lane & 15, quad = lane >> 4;
    const int q0 = blockIdx.x * 128 + wg * 32;
    const int c7 = col & 7;

    const __hip_bfloat16* Qh = Q + (size_t)bh * 4096 * 64;
    const __hip_bfloat16* Kh = Kq + (size_t)bh * 4096 * 64 + (size_t)g * 2048 * 64;
    const __hip_bfloat16* Vh = Vt + (size_t)bh * 64 * 4096 + (size_t)g * 2048;

    // Q B-operand frags: lane holds Q[q0+qh*16+col][ks*32+quad*8 .. +7]
    bf16x8 aq[2][2];
    for (int qh = 0; qh < 2; ++qh)
        for (int ks = 0; ks < 2; ++ks)
            aq[qh][ks] = *reinterpret_cast<const bf16x8*>(
                Qh + (size_t)(q0 + qh * 16 + col) * 64 + ks * 32 + quad * 8);

    // staging (per group, 256 threads): chunk c = i*256 + wg*64 + lane
    const __hip_bfloat16* ksrc[2];
    const __hip_bfloat16* vsrc[2];
    int ldsoff[2];
    for (int i = 0; i < 2; ++i) {
        int c = i * 256 + wg * 64 + lane;
        int row = c >> 3, s8 = (c & 7) ^ (row & 7);
        ksrc[i] = Kh + row * 64 + s8 * 8;
        vsrc[i] = Vh + (size_t)row * 4096 + s8 * 8;
        ldsoff[i] = (i * 256 + wg * 64) * 8;   // wave-uniform LDS base (elems)
    }

    bf16x8 ones;
    for (int j = 0; j < 8; ++j) ones[j] = (__bf16)1.0f;

    f32x4 o[4][2] = {};     // O^T[d=dt*16+quad*4+r][q=qh*16+col] (partial: this key half)
    f32x4 accl[2] = {};     // partial denominators (ones-MFMA)
    f32x4 sc[4][2];         // score tile S^T

    uint32_t* TBw = &TB[w][0];
    uint2* TBw2 = reinterpret_cast<uint2*>(TBw);

#define SOFTMAX_STORE(QH_)                                                      \
    for (int kg = 0; kg < 4; ++kg) {                                            \
        f32x4 v = sc[kg][(QH_)];                                                \
        uint2 u;                                                                \
        u.x = pkbf(__builtin_amdgcn_exp2f(v[0]), __builtin_amdgcn_exp2f(v[1])); \
        u.y = pkbf(__builtin_amdgcn_exp2f(v[2]), __builtin_amdgcn_exp2f(v[3])); \
        TBw2[col * 16 + (((kg * 2 + (quad >> 1)) ^ c7) << 1) + (quad & 1)] = u; \
    }
#define BP_READ(QH_)                                                            \
    for (int ks = 0; ks < 2; ++ks)                                              \
        bp[(QH_)][ks] = *reinterpret_cast<const bf16x8*>(                       \
            &TBw[col * 32 + (((ks * 4 + quad) ^ c7) << 2)]);

#define QK_TILE(P_)                                                             \
    for (int kg = 0; kg < 4; ++kg)                                              \
        for (int qh = 0; qh < 2; ++qh)                                          \
            sc[kg][qh] = (f32x4){0.f, 0.f, 0.f, 0.f};                           \
    for (int ks = 0; ks < 2; ++ks)                                              \
        for (int kg = 0; kg < 4; ++kg) {                                        \
            bf16x8 ak = *reinterpret_cast<const bf16x8*>(                       \
                &KT[g][(P_)][(kg * 16 + col) * 64 + (((ks * 4 + quad) ^ c7) << 3)]); \
            for (int qh = 0; qh < 2; ++qh)                                      \
                sc[kg][qh] = mfma16(ak, aq[qh][ks], sc[kg][qh]);                \
        }

#define PV_TILE(P_)                                                             \
    for (int ks = 0; ks < 2; ++ks) {                                            \
        for (int dt = 0; dt < 4; ++dt) {                                        \
            bf16x8 av = *reinterpret_cast<const bf16x8*>(                       \
                &VB[g][(P_)][(dt * 16 + col) * 64 + (((ks * 4 + quad) ^ c7) << 3)]); \
            for (int qh = 0; qh < 2; ++qh)                                      \
                o[dt][qh] = mfma16(av, bp[qh][ks], o[dt][qh]);                  \
        }                                                                       \
        accl[0] = mfma16(ones, bp[0][ks], accl[0]);                             \
        accl[1] = mfma16(ones, bp[1][ks], accl[1]);                             \
    }

#define FLASH_BODY(KT_, P_)                                                     \
    {                                                                           \
        const int kt_ = (KT_);                                                  \
        gload16(ksrc[0] + (size_t)(kt_ + 1) * 4096, &KT[g][1 - (P_)][ldsoff[0]]); \
        gload16(ksrc[1] + (size_t)(kt_ + 1) * 4096, &KT[g][1 - (P_)][ldsoff[1]]); \
        gload16(vsrc[0] + (size_t)(kt_ + 1) * 64, &VB[g][1 - (P_)][ldsoff[0]]); \
        gload16(vsrc[1] + (size_t)(kt_ + 1) * 64, &VB[g][1 - (P_)][ldsoff[1]]); \
        QK_TILE(P_)                                                             \
        bf16x8 bp[2][2];                                                        \
        SOFTMAX_STORE(0) BP_READ(0) SOFTMAX_STORE(1) BP_READ(1)                 \
        PV_TILE(P_)                                                             \
        __syncthreads();                                                        \
    }

    // prologue: stage tile 0 (parity 0)
    gload16(ksrc[0], &KT[g][0][ldsoff[0]]);
    gload16(ksrc[1], &KT[g][0][ldsoff[1]]);
    gload16(vsrc[0], &VB[g][0][ldsoff[0]]);
    gload16(vsrc[1], &VB[g][0][ldsoff[1]]);
    __syncthreads();

    FLASH_BODY(0, 0)
    for (int kth = 0; kth < 15; ++kth) {
        FLASH_BODY(2 * kth + 1, 1)
        FLASH_BODY(2 * kth + 2, 0)
    }
    // bodies covered kt=0..30; tile 31 (parity 1), no staging, no barrier:
    {
        QK_TILE(1)
        bf16x8 bp[2][2];
        SOFTMAX_STORE(0) BP_READ(0) SOFTMAX_STORE(1) BP_READ(1)
        PV_TILE(1)
    }
#undef FLASH_BODY
#undef QK_TILE
#undef PV_TILE
#undef SOFTMAX_STORE
#undef BP_READ

    // ---- merge the two key-halves (partials are additive: fixed-max softmax)
    __syncthreads();   // all KT/VB/TB reads complete
    float* MB = reinterpret_cast<float*>(&KT[0][0][0]);   // 32 KB, dead
    float* Lb = reinterpret_cast<float*>(&TB[0][0]);      // small, dead
    // layout: addr = wg*2048 + q_lo*64 + ((d>>2)^q_lo)*4 + (d&3)   (conflict-free)
    if (g == 1) {
        float* M = MB + wg * 2048;
        for (int qh = 0; qh < 2; ++qh)
            for (int dt = 0; dt < 4; ++dt)
                *reinterpret_cast<f32x4*>(
                    M + (qh * 16 + col) * 64 + (((dt * 4 + quad) ^ col) << 2)) = o[dt][qh];
        if (quad == 0) {
            Lb[wg * 32 + col]      = accl[0][0];
            Lb[wg * 32 + 16 + col] = accl[1][0];
        }
    }
    __syncthreads();
    if (g == 0) {
        float* M = MB + wg * 2048;
        for (int qh = 0; qh < 2; ++qh) {
            float l = accl[qh][0] + Lb[wg * 32 + qh * 16 + col];
            float inv = 1.0f / l;
            int s = q0 + qh * 16 + col;
            __hip_bfloat16* dst = attnb + ((size_t)b * 4096 + s) * 512 + h * 64 + quad * 4;
            for (int dt = 0; dt < 4; ++dt) {
                f32x4 p = o[dt][qh] + *reinterpret_cast<const f32x4*>(
                    M + (qh * 16 + col) * 64 + (((dt * 4 + quad) ^ col) << 2));
                union { __hip_bfloat16 hh[4]; ushort4 v4; } pk;
                for (int r = 0; r < 4; ++r)
                    pk.hh[r] = __float2bfloat16(p[r] * inv);
                *reinterpret_cast<ushort4*>(dst + dt * 16) = pk.v4;
            }
        }
    }
}

// ---------------------------------------------------------------- launch
extern "C" void kernel_launch(void* const* d_in, const int* in_sizes, int n_in,
                              void* d_out, int out_size, void* d_ws, size_t ws_size,
                              hipStream_t stream) {
    const float* X  = (const float*)d_in[0];
    const float* Wq = (const float*)d_in[1];
    const float* bq = (const float*)d_in[2];
    const float* Wk = (const float*)d_in[3];
    const float* bk = (const float*)d_in[4];
    const float* Wv = (const float*)d_in[5];
    const float* bv = (const float*)d_in[6];
    const float* Wo = (const float*)d_in[7];
    const float* bo = (const float*)d_in[8];
    float* out = (float*)d_out;

    char* ws = (char*)d_ws;
    __hip_bfloat16* Xb  = (__hip_bfloat16*)(ws);
    __hip_bfloat16* Wqt = (__hip_bfloat16*)(ws + ((size_t)8 << 20));
    __hip_bfloat16* Wkt = Wqt + 512 * 512;
    __hip_bfloat16* Wvt = Wkt + 512 * 512;
    __hip_bfloat16* Wot = Wvt + 512 * 512;
    __hip_bfloat16* Qb  = (__hip_bfloat16*)(ws + ((size_t)10 << 20));
    __hip_bfloat16* Kb  = (__hip_bfloat16*)(ws + ((size_t)18 << 20));
    __hip_bfloat16* Vtb = (__hip_bfloat16*)(ws + ((size_t)26 << 20));
    __hip_bfloat16* Atb = (__hip_bfloat16*)(ws + ((size_t)34 << 20));

    const int M = 8192, K = 512;

    cvt_x<<<4096, 256, 0, stream>>>(X, Xb, M * K);
    cvt_wt<<<dim3(16, 16, 4), dim3(32, 8), 0, stream>>>(Wq, Wk, Wv, Wo, Wqt, Wkt, Wvt, Wot);

    const float qs = 0.125f * 1.4426950408889634f;  // (1/sqrt(64)) * log2(e), folded into Q
    gemm_qkv<<<dim3(12, 64), 256, 0, stream>>>(Xb, Wqt, bq, bk, bv, Qb, Kb, Vtb, qs);

    flash<<<dim3(32, 16), 512, 0, stream>>>(Qb, Kb, Vtb, Atb);

    gemm_out<<<dim3(8, 64), 256, 0, stream>>>(Atb, Wot, bo, out);
}

// Round 6
// 223.101 us; speedup vs baseline: 1.0671x; 1.0671x over previous
//
#include <hip/hip_runtime.h>
#include <hip/hip_bf16.h>
#include <stdint.h>

// Problem: B=2, S=4096, D=512, H=8, hd=64. fp32 in/out, bf16 MFMA internally.
//
// ws layout (42 MB total):
//   [0,   8MB)  Xb    bf16 [8192,512]       input cast
//   [8,  10MB)  Wqt/Wkt/Wvt/Wot bf16 [512,512] each (transposed [N,K]; QKV contiguous)
//   [10, 18MB)  Qb    bf16 [B,H,S,64]  (pre-scaled by 0.125*log2e)
//   [18, 26MB)  Kb    bf16 [B,H,S,64]
//   [26, 34MB)  Vtb   bf16 [B,H,64,S]  (transposed for PV A-operand)
//   [34, 42MB)  Atb   bf16 [B,S,512]   attention output (pre-Wo)

typedef __bf16 bf16x8 __attribute__((ext_vector_type(8)));
typedef float f32x4 __attribute__((ext_vector_type(4)));

using as1_void = __attribute__((address_space(1))) void;
using as3_void = __attribute__((address_space(3))) void;

__device__ __forceinline__ void gload16(const void* g, void* l) {
    __builtin_amdgcn_global_load_lds((const as1_void*)g, (as3_void*)l, 16, 0, 0);
}

__device__ __forceinline__ f32x4 mfma16(bf16x8 a, bf16x8 b, f32x4 c) {
    return __builtin_amdgcn_mfma_f32_16x16x32_bf16(a, b, c, 0, 0, 0);
}

__device__ __forceinline__ uint32_t pkbf(float a, float b) {
    union { __hip_bfloat16 h[2]; uint32_t u; } r;
    r.h[0] = __float2bfloat16(a);   // low 16 = even element
    r.h[1] = __float2bfloat16(b);
    return r.u;
}

// ---------------------------------------------------------------- converts (fused)
// blocks [0,1024): weight transposes (256 blocks per weight, 32x32 tiles)
// blocks [1024,5120): X fp32 -> bf16 cast (4 elems/thread)
__global__ void cvt_all(const float* __restrict__ X, __hip_bfloat16* __restrict__ Xb,
                        const float* __restrict__ w0, const float* __restrict__ w1,
                        const float* __restrict__ w2, const float* __restrict__ w3,
                        __hip_bfloat16* __restrict__ o0, __hip_bfloat16* __restrict__ o1,
                        __hip_bfloat16* __restrict__ o2, __hip_bfloat16* __restrict__ o3) {
    __shared__ float t[32][33];
    const int bid = blockIdx.x, tid = threadIdx.x;
    if (bid < 1024) {
        const float* W; __hip_bfloat16* O;
        switch (bid >> 8) {
            case 0: W = w0; O = o0; break;
            case 1: W = w1; O = o1; break;
            case 2: W = w2; O = o2; break;
            default: W = w3; O = o3; break;
        }
        int rem = bid & 255;
        int n0 = (rem & 15) * 32, k0 = (rem >> 4) * 32;
        int tx = tid & 31, ty = tid >> 5;
        for (int j = 0; j < 4; ++j)
            t[ty + 8 * j][tx] = W[(size_t)(k0 + ty + 8 * j) * 512 + n0 + tx];
        __syncthreads();
        for (int j = 0; j < 4; ++j)
            O[(size_t)(n0 + ty + 8 * j) * 512 + k0 + tx] = __float2bfloat16(t[tx][ty + 8 * j]);
    } else {
        int i = ((bid - 1024) * 256 + tid) * 4;   // covers exactly 8192*512
        float4 v = *reinterpret_cast<const float4*>(X + i);
        union { __hip_bfloat16 h[4]; uint2 u; } r;
        r.h[0] = __float2bfloat16(v.x);
        r.h[1] = __float2bfloat16(v.y);
        r.h[2] = __float2bfloat16(v.z);
        r.h[3] = __float2bfloat16(v.w);
        *reinterpret_cast<uint2*>(Xb + i) = r.u;
    }
}

// ---------------------------------------------------------------- fused QKV GEMM
__global__ __launch_bounds__(256, 2) void gemm_qkv(
    const __hip_bfloat16* __restrict__ A, const __hip_bfloat16* __restrict__ Bt,
    const float* __restrict__ bq, const float* __restrict__ bk, const float* __restrict__ bv,
    __hip_bfloat16* __restrict__ Qb, __hip_bfloat16* __restrict__ Kb,
    __hip_bfloat16* __restrict__ Vtb, float qs)
{
    const int K = 512;
    __shared__ __hip_bfloat16 Abuf[128 * 32];
    __shared__ __hip_bfloat16 Bbuf[128 * 32];
    const int tid = threadIdx.x, w = tid >> 6, lane = tid & 63;
    const int col = lane & 15, quad = lane >> 4;
    const int wr = w >> 1, wc = w & 1;
    const int tileN = blockIdx.x * 128, tileM = blockIdx.y * 128;

    f32x4 acc[4][4] = {};

    for (int k0 = 0; k0 < K; k0 += 32) {
        for (int i = 0; i < 2; ++i) {
            int g = w * 2 + i;
            int chunk = g * 64 + lane;
            int row = chunk >> 2, c8 = chunk & 3;
            gload16(A + (size_t)(tileM + row) * K + k0 + c8 * 8, Abuf + g * 512);
            gload16(Bt + (size_t)(tileN + row) * K + k0 + c8 * 8, Bbuf + g * 512);
        }
        __syncthreads();
        bf16x8 af[4], bfr[4];
        for (int mt = 0; mt < 4; ++mt)
            af[mt] = *reinterpret_cast<const bf16x8*>(Abuf + (wr * 64 + mt * 16 + col) * 32 + quad * 8);
        for (int nt = 0; nt < 4; ++nt)
            bfr[nt] = *reinterpret_cast<const bf16x8*>(Bbuf + (wc * 64 + nt * 16 + col) * 32 + quad * 8);
        for (int mt = 0; mt < 4; ++mt)
            for (int nt = 0; nt < 4; ++nt)
                acc[mt][nt] = mfma16(af[mt], bfr[nt], acc[mt][nt]);
        __syncthreads();
    }

    const int seg = (tileN + wc * 64) >> 9;   // wave-uniform
    const float* bias = (seg == 0) ? bq : (seg == 1) ? bk : bv;
    const float scale = (seg == 0) ? qs : 1.0f;
    __hip_bfloat16* outp = (seg == 0) ? Qb : (seg == 1) ? Kb : Vtb;

    for (int mt = 0; mt < 4; ++mt) {
        for (int nt = 0; nt < 4; ++nt) {
            int n = tileN + wc * 64 + nt * 16 + col;
            int nn = n & 511, h = nn >> 6, d = nn & 63;
            float bn = bias[nn];
            for (int r = 0; r < 4; ++r) {
                int m = tileM + wr * 64 + mt * 16 + quad * 4 + r;
                int b = m >> 12, s = m & 4095;
                float v = (acc[mt][nt][r] + bn) * scale;
                size_t off;
                if (seg < 2) off = (((size_t)(b * 8 + h) * 4096 + s) << 6) + d;
                else         off = (((size_t)(b * 8 + h) * 64 + d) << 12) + s;
                outp[off] = __float2bfloat16(v);
            }
        }
    }
}

// ---------------------------------------------------------------- final GEMM (Wo)
// 128(M) x 64(N) tiles -> 512 blocks = 2 blocks/CU.
__global__ __launch_bounds__(256, 2) void gemm_out(
    const __hip_bfloat16* __restrict__ A, const __hip_bfloat16* __restrict__ Bt,
    const float* __restrict__ bias, float* __restrict__ out)
{
    const int N = 512, K = 512;
    __shared__ __hip_bfloat16 Abuf[128 * 32];
    __shared__ __hip_bfloat16 Bbuf[64 * 32];
    const int tid = threadIdx.x, w = tid >> 6, lane = tid & 63;
    const int col = lane & 15, quad = lane >> 4;
    const int tileN = blockIdx.x * 64, tileM = blockIdx.y * 128;

    f32x4 acc[2][4] = {};

    for (int k0 = 0; k0 < K; k0 += 32) {
        for (int i = 0; i < 2; ++i) {
            int g = w * 2 + i;
            int chunk = g * 64 + lane;
            int row = chunk >> 2, c8 = chunk & 3;
            gload16(A + (size_t)(tileM + row) * K + k0 + c8 * 8, Abuf + g * 512);
        }
        {
            int row = tid >> 2, c8 = tid & 3;
            gload16(Bt + (size_t)(tileN + row) * K + k0 + c8 * 8, Bbuf + tid * 8);
        }
        __syncthreads();
        bf16x8 af[2], bfr[4];
        for (int mt = 0; mt < 2; ++mt)
            af[mt] = *reinterpret_cast<const bf16x8*>(Abuf + (w * 32 + mt * 16 + col) * 32 + quad * 8);
        for (int nt = 0; nt < 4; ++nt)
            bfr[nt] = *reinterpret_cast<const bf16x8*>(Bbuf + (nt * 16 + col) * 32 + quad * 8);
        for (int mt = 0; mt < 2; ++mt)
            for (int nt = 0; nt < 4; ++nt)
                acc[mt][nt] = mfma16(af[mt], bfr[nt], acc[mt][nt]);
        __syncthreads();
    }

    for (int mt = 0; mt < 2; ++mt) {
        for (int nt = 0; nt < 4; ++nt) {
            int n = tileN + nt * 16 + col;
            float bn = bias[n];
            for (int r = 0; r < 4; ++r) {
                int m = tileM + w * 32 + mt * 16 + quad * 4 + r;
                out[(size_t)m * N + n] = acc[mt][nt][r] + bn;
            }
        }
    }
}

// ---------------------------------------------------------------- flash attention (v6)
// = v5 structure (512 threads, 2 key-groups x 4 waves, additive fixed-max
// partials, LDS merge) with the launch-bounds register budget FIXED:
// __launch_bounds__(512, 2) -> >=128 VGPR/wave allowed. R5's (512,4) forced
// 64 VGPRs -> scratch spills (WRITE_SIZE 8->94 MB, FETCH 70->123 MB). LDS
// (80 KB) caps residency at 2 blocks/CU = 4 waves/SIMD either way.
__global__ __launch_bounds__(512, 2) void flash(
    const __hip_bfloat16* __restrict__ Q,   // [B*H, 4096, 64] (pre-scaled)
    const __hip_bfloat16* __restrict__ Kq,  // [B*H, 4096, 64]
    const __hip_bfloat16* __restrict__ Vt,  // [B*H, 64, 4096]
    __hip_bfloat16* __restrict__ attnb)     // [B, 4096, 512]
{
    __shared__ __hip_bfloat16 KT[2][2][4096];  // [group][parity] 32 KB
    __shared__ __hip_bfloat16 VB[2][2][4096];  // 32 KB
    __shared__ uint32_t TB[8][512];            // 16 KB per-wave P^T staging (one qh at a time)

    const int bh = blockIdx.y, b = bh >> 3, h = bh & 7;
    const int tid = threadIdx.x, w = tid >> 6, lane = tid & 63;
    const int g = w >> 2, wg = w & 3;
    const int col = lane & 15, quad = lane >> 4;
    const int q0 = blockIdx.x * 128 + wg * 32;
    const int c7 = col & 7;

    const __hip_bfloat16* Qh = Q + (size_t)bh * 4096 * 64;
    const __hip_bfloat16* Kh = Kq + (size_t)bh * 4096 * 64 + (size_t)g * 2048 * 64;
    const __hip_bfloat16* Vh = Vt + (size_t)bh * 64 * 4096 + (size_t)g * 2048;

    // Q B-operand frags: lane holds Q[q0+qh*16+col][ks*32+quad*8 .. +7]
    bf16x8 aq[2][2];
    for (int qh = 0; qh < 2; ++qh)
        for (int ks = 0; ks < 2; ++ks)
            aq[qh][ks] = *reinterpret_cast<const bf16x8*>(
                Qh + (size_t)(q0 + qh * 16 + col) * 64 + ks * 32 + quad * 8);

    // staging (per group, 256 threads): chunk c = i*256 + wg*64 + lane
    const __hip_bfloat16* ksrc[2];
    const __hip_bfloat16* vsrc[2];
    int ldsoff[2];
    for (int i = 0; i < 2; ++i) {
        int c = i * 256 + wg * 64 + lane;
        int row = c >> 3, s8 = (c & 7) ^ (row & 7);
        ksrc[i] = Kh + row * 64 + s8 * 8;
        vsrc[i] = Vh + (size_t)row * 4096 + s8 * 8;
        ldsoff[i] = (i * 256 + wg * 64) * 8;   // wave-uniform LDS base (elems)
    }

    bf16x8 ones;
    for (int j = 0; j < 8; ++j) ones[j] = (__bf16)1.0f;

    f32x4 o[4][2] = {};     // O^T[d=dt*16+quad*4+r][q=qh*16+col] (partial: this key half)
    f32x4 accl[2] = {};     // partial denominators (ones-MFMA)
    f32x4 sc[4][2];         // score tile S^T

    uint32_t* TBw = &TB[w][0];
    uint2* TBw2 = reinterpret_cast<uint2*>(TBw);

#define SOFTMAX_STORE(QH_)                                                      \
    for (int kg = 0; kg < 4; ++kg) {                                            \
        f32x4 v = sc[kg][(QH_)];                                                \
        uint2 u;                                                                \
        u.x = pkbf(__builtin_amdgcn_exp2f(v[0]), __builtin_amdgcn_exp2f(v[1])); \
        u.y = pkbf(__builtin_amdgcn_exp2f(v[2]), __builtin_amdgcn_exp2f(v[3])); \
        TBw2[col * 16 + (((kg * 2 + (quad >> 1)) ^ c7) << 1) + (quad & 1)] = u; \
    }
#define BP_READ(QH_)                                                            \
    for (int ks = 0; ks < 2; ++ks)                                              \
        bp[(QH_)][ks] = *reinterpret_cast<const bf16x8*>(                       \
            &TBw[col * 32 + (((ks * 4 + quad) ^ c7) << 2)]);

#define QK_TILE(P_)                                                             \
    for (int kg = 0; kg < 4; ++kg)                                              \
        for (int qh = 0; qh < 2; ++qh)                                          \
            sc[kg][qh] = (f32x4){0.f, 0.f, 0.f, 0.f};                           \
    for (int ks = 0; ks < 2; ++ks)                                              \
        for (int kg = 0; kg < 4; ++kg) {                                        \
            bf16x8 ak = *reinterpret_cast<const bf16x8*>(                       \
                &KT[g][(P_)][(kg * 16 + col) * 64 + (((ks * 4 + quad) ^ c7) << 3)]); \
            for (int qh = 0; qh < 2; ++qh)                                      \
                sc[kg][qh] = mfma16(ak, aq[qh][ks], sc[kg][qh]);                \
        }

#define PV_TILE(P_)                                                             \
    for (int ks = 0; ks < 2; ++ks) {                                            \
        for (int dt = 0; dt < 4; ++dt) {                                        \
            bf16x8 av = *reinterpret_cast<const bf16x8*>(                       \
                &VB[g][(P_)][(dt * 16 + col) * 64 + (((ks * 4 + quad) ^ c7) << 3)]); \
            for (int qh = 0; qh < 2; ++qh)                                      \
                o[dt][qh] = mfma16(av, bp[qh][ks], o[dt][qh]);                  \
        }                                                                       \
        accl[0] = mfma16(ones, bp[0][ks], accl[0]);                             \
        accl[1] = mfma16(ones, bp[1][ks], accl[1]);                             \
    }

#define FLASH_BODY(KT_, P_)                                                     \
    {                                                                           \
        const int kt_ = (KT_);                                                  \
        gload16(ksrc[0] + (size_t)(kt_ + 1) * 4096, &KT[g][1 - (P_)][ldsoff[0]]); \
        gload16(ksrc[1] + (size_t)(kt_ + 1) * 4096, &KT[g][1 - (P_)][ldsoff[1]]); \
        gload16(vsrc[0] + (size_t)(kt_ + 1) * 64, &VB[g][1 - (P_)][ldsoff[0]]); \
        gload16(vsrc[1] + (size_t)(kt_ + 1) * 64, &VB[g][1 - (P_)][ldsoff[1]]); \
        QK_TILE(P_)                                                             \
        bf16x8 bp[2][2];                                                        \
        SOFTMAX_STORE(0) BP_READ(0) SOFTMAX_STORE(1) BP_READ(1)                 \
        PV_TILE(P_)                                                             \
        __syncthreads();                                                        \
    }

    // prologue: stage tile 0 (parity 0)
    gload16(ksrc[0], &KT[g][0][ldsoff[0]]);
    gload16(ksrc[1], &KT[g][0][ldsoff[1]]);
    gload16(vsrc[0], &VB[g][0][ldsoff[0]]);
    gload16(vsrc[1], &VB[g][0][ldsoff[1]]);
    __syncthreads();

    FLASH_BODY(0, 0)
    for (int kth = 0; kth < 15; ++kth) {
        FLASH_BODY(2 * kth + 1, 1)
        FLASH_BODY(2 * kth + 2, 0)
    }
    // bodies covered kt=0..30; tile 31 (parity 1), no staging, no barrier:
    {
        QK_TILE(1)
        bf16x8 bp[2][2];
        SOFTMAX_STORE(0) BP_READ(0) SOFTMAX_STORE(1) BP_READ(1)
        PV_TILE(1)
    }
#undef FLASH_BODY
#undef QK_TILE
#undef PV_TILE
#undef SOFTMAX_STORE
#undef BP_READ

    // ---- merge the two key-halves (partials are additive: fixed-max softmax)
    __syncthreads();   // all KT/VB/TB reads complete
    float* MB = reinterpret_cast<float*>(&KT[0][0][0]);   // 32 KB, dead
    float* Lb = reinterpret_cast<float*>(&TB[0][0]);      // small, dead
    // layout: addr = wg*2048 + q_lo*64 + ((d>>2)^q_lo)*4 + (d&3)   (conflict-free)
    if (g == 1) {
        float* M = MB + wg * 2048;
        for (int qh = 0; qh < 2; ++qh)
            for (int dt = 0; dt < 4; ++dt)
                *reinterpret_cast<f32x4*>(
                    M + (qh * 16 + col) * 64 + (((dt * 4 + quad) ^ col) << 2)) = o[dt][qh];
        if (quad == 0) {
            Lb[wg * 32 + col]      = accl[0][0];
            Lb[wg * 32 + 16 + col] = accl[1][0];
        }
    }
    __syncthreads();
    if (g == 0) {
        float* M = MB + wg * 2048;
        for (int qh = 0; qh < 2; ++qh) {
            float l = accl[qh][0] + Lb[wg * 32 + qh * 16 + col];
            float inv = 1.0f / l;
            int s = q0 + qh * 16 + col;
            __hip_bfloat16* dst = attnb + ((size_t)b * 4096 + s) * 512 + h * 64 + quad * 4;
            for (int dt = 0; dt < 4; ++dt) {
                f32x4 p = o[dt][qh] + *reinterpret_cast<const f32x4*>(
                    M + (qh * 16 + col) * 64 + (((dt * 4 + quad) ^ col) << 2));
                union { __hip_bfloat16 hh[4]; ushort4 v4; } pk;
                for (int r = 0; r < 4; ++r)
                    pk.hh[r] = __float2bfloat16(p[r] * inv);
                *reinterpret_cast<ushort4*>(dst + dt * 16) = pk.v4;
            }
        }
    }
}

// ---------------------------------------------------------------- launch
extern "C" void kernel_launch(void* const* d_in, const int* in_sizes, int n_in,
                              void* d_out, int out_size, void* d_ws, size_t ws_size,
                              hipStream_t stream) {
    const float* X  = (const float*)d_in[0];
    const float* Wq = (const float*)d_in[1];
    const float* bq = (const float*)d_in[2];
    const float* Wk = (const float*)d_in[3];
    const float* bk = (const float*)d_in[4];
    const float* Wv = (const float*)d_in[5];
    const float* bv = (const float*)d_in[6];
    const float* Wo = (const float*)d_in[7];
    const float* bo = (const float*)d_in[8];
    float* out = (float*)d_out;

    char* ws = (char*)d_ws;
    __hip_bfloat16* Xb  = (__hip_bfloat16*)(ws);
    __hip_bfloat16* Wqt = (__hip_bfloat16*)(ws + ((size_t)8 << 20));
    __hip_bfloat16* Wkt = Wqt + 512 * 512;
    __hip_bfloat16* Wvt = Wkt + 512 * 512;
    __hip_bfloat16* Wot = Wvt + 512 * 512;
    __hip_bfloat16* Qb  = (__hip_bfloat16*)(ws + ((size_t)10 << 20));
    __hip_bfloat16* Kb  = (__hip_bfloat16*)(ws + ((size_t)18 << 20));
    __hip_bfloat16* Vtb = (__hip_bfloat16*)(ws + ((size_t)26 << 20));
    __hip_bfloat16* Atb = (__hip_bfloat16*)(ws + ((size_t)34 << 20));

    cvt_all<<<5120, 256, 0, stream>>>(X, Xb, Wq, Wk, Wv, Wo, Wqt, Wkt, Wvt, Wot);

    const float qs = 0.125f * 1.4426950408889634f;  // (1/sqrt(64)) * log2(e), folded into Q
    gemm_qkv<<<dim3(12, 64), 256, 0, stream>>>(Xb, Wqt, bq, bk, bv, Qb, Kb, Vtb, qs);

    flash<<<dim3(32, 16), 512, 0, stream>>>(Qb, Kb, Vtb, Atb);

    gemm_out<<<dim3(8, 64), 256, 0, stream>>>(Atb, Wot, bo, out);
}

// Round 7
// 222.993 us; speedup vs baseline: 1.0677x; 1.0005x over previous
//
#include <hip/hip_runtime.h>
#include <hip/hip_bf16.h>
#include <stdint.h>

// Problem: B=2, S=4096, D=512, H=8, hd=64. fp32 in/out, bf16 MFMA internally.
// 3 dispatches: gemm_qkv (fp32 X,W in; bf16 Q/K/Vt out) -> flash -> gemm_out.
//
// ws layout:
//   [10, 18MB)  Qb    bf16 [B,H,S,64]  (pre-scaled by 0.125*log2e)
//   [18, 26MB)  Kb    bf16 [B,H,S,64]
//   [26, 34MB)  Vtb   bf16 [B,H,64,S]  (transposed for PV A-operand)
//   [34, 42MB)  Atb   bf16 [B,S,512]   attention output (pre-Wo)

typedef __bf16 bf16x8 __attribute__((ext_vector_type(8)));
typedef float f32x4 __attribute__((ext_vector_type(4)));

using as1_void = __attribute__((address_space(1))) void;
using as3_void = __attribute__((address_space(3))) void;

__device__ __forceinline__ void gload16(const void* g, void* l) {
    __builtin_amdgcn_global_load_lds((const as1_void*)g, (as3_void*)l, 16, 0, 0);
}

__device__ __forceinline__ f32x4 mfma16(bf16x8 a, bf16x8 b, f32x4 c) {
    return __builtin_amdgcn_mfma_f32_16x16x32_bf16(a, b, c, 0, 0, 0);
}

__device__ __forceinline__ uint32_t pkbf(float a, float b) {
    union { __hip_bfloat16 h[2]; uint32_t u; } r;
    r.h[0] = __float2bfloat16(a);   // low 16 = even element
    r.h[1] = __float2bfloat16(b);
    return r.u;
}

// ---------------------------------------------------------------- fused QKV GEMM
// Reads X fp32 [8192,512] and Wq/Wk/Wv fp32 [512,512] ([k][n] layout) directly;
// staging converts to bf16 and transposes W on the fly (no cvt prepass, no
// Xb/Wt HBM round-trip). grid (12, 64): blockIdx.x>>2 selects W, tile 128x128.
// B LDS layout [n][k] with group-XOR swizzle on the 4-u32 k-group to spread
// scatter-write banks: u32 addr = n*16 + (((kp>>2) ^ (part&3))<<2) + (kp&3).
__global__ __launch_bounds__(256, 3) void gemm_qkv(
    const float* __restrict__ X,
    const float* __restrict__ Wq, const float* __restrict__ Wk, const float* __restrict__ Wv,
    const float* __restrict__ bq, const float* __restrict__ bk, const float* __restrict__ bv,
    __hip_bfloat16* __restrict__ Qb, __hip_bfloat16* __restrict__ Kb,
    __hip_bfloat16* __restrict__ Vtb, float qs)
{
    __shared__ __hip_bfloat16 Abuf[128 * 32];   // [m][k] row-major
    __shared__ __hip_bfloat16 Bbuf[128 * 32];   // [n][k] swizzled (see above)
    const int tid = threadIdx.x, w = tid >> 6, lane = tid & 63;
    const int col = lane & 15, quad = lane >> 4;
    const int wr = w >> 1, wc = w & 1;
    const int tileN = blockIdx.x * 128, tileM = blockIdx.y * 128;
    const int seg = blockIdx.x >> 2;            // 0=Q 1=K 2=V
    const int nb0 = tileN & 511;                // column base within W
    const float* W = (seg == 0) ? Wq : (seg == 1) ? Wk : Wv;

    // A staging map: thread t covers row=t>>1, half=(t&1)*16 of [128][32]
    const int arow = tid >> 1, ah = (tid & 1) * 16;
    // B staging map: kp=t>>4 (16 k-pairs), part=t&15 (8 n's each)
    const int kp = tid >> 4, part = tid & 15;
    const int bgrp = (((kp >> 2) ^ (part & 3)) << 2) + (kp & 3);  // swizzled u32 slot
    uint32_t* B32 = reinterpret_cast<uint32_t*>(Bbuf);

    f32x4 acc[4][4] = {};

    for (int k0 = 0; k0 < 512; k0 += 32) {
        // ---- stage A: X fp32 -> bf16, row-major
        const float* ap = X + (size_t)(tileM + arow) * 512 + k0 + ah;
        float4 a0 = *reinterpret_cast<const float4*>(ap);
        float4 a1 = *reinterpret_cast<const float4*>(ap + 4);
        float4 a2 = *reinterpret_cast<const float4*>(ap + 8);
        float4 a3 = *reinterpret_cast<const float4*>(ap + 12);
        union { uint32_t u[4]; int4 v; } pa0, pa1;
        pa0.u[0] = pkbf(a0.x, a0.y); pa0.u[1] = pkbf(a0.z, a0.w);
        pa0.u[2] = pkbf(a1.x, a1.y); pa0.u[3] = pkbf(a1.z, a1.w);
        pa1.u[0] = pkbf(a2.x, a2.y); pa1.u[1] = pkbf(a2.z, a2.w);
        pa1.u[2] = pkbf(a3.x, a3.y); pa1.u[3] = pkbf(a3.z, a3.w);
        // ---- stage B: W fp32 [k][n] -> bf16 [n][k], coalesced reads, swizzled scatter
        const float* bp0 = W + (size_t)(k0 + 2 * kp) * 512 + nb0 + part * 8;
        float4 b00 = *reinterpret_cast<const float4*>(bp0);
        float4 b01 = *reinterpret_cast<const float4*>(bp0 + 4);
        float4 b10 = *reinterpret_cast<const float4*>(bp0 + 512);
        float4 b11 = *reinterpret_cast<const float4*>(bp0 + 516);
        *reinterpret_cast<int4*>(Abuf + arow * 32 + ah) = pa0.v;
        *reinterpret_cast<int4*>(Abuf + arow * 32 + ah + 8) = pa1.v;
        B32[(part * 8 + 0) * 16 + bgrp] = pkbf(b00.x, b10.x);
        B32[(part * 8 + 1) * 16 + bgrp] = pkbf(b00.y, b10.y);
        B32[(part * 8 + 2) * 16 + bgrp] = pkbf(b00.z, b10.z);
        B32[(part * 8 + 3) * 16 + bgrp] = pkbf(b00.w, b10.w);
        B32[(part * 8 + 4) * 16 + bgrp] = pkbf(b01.x, b11.x);
        B32[(part * 8 + 5) * 16 + bgrp] = pkbf(b01.y, b11.y);
        B32[(part * 8 + 6) * 16 + bgrp] = pkbf(b01.z, b11.z);
        B32[(part * 8 + 7) * 16 + bgrp] = pkbf(b01.w, b11.w);
        __syncthreads();

        bf16x8 af[4], bfr[4];
        for (int mt = 0; mt < 4; ++mt)
            af[mt] = *reinterpret_cast<const bf16x8*>(
                Abuf + (wr * 64 + mt * 16 + col) * 32 + quad * 8);
        for (int nt = 0; nt < 4; ++nt) {
            int n = wc * 64 + nt * 16 + col;
            int g = quad ^ ((2 * nt + (col >> 3)) & 3);
            bfr[nt] = *reinterpret_cast<const bf16x8*>(Bbuf + n * 32 + g * 8);
        }
        for (int mt = 0; mt < 4; ++mt)
            for (int nt = 0; nt < 4; ++nt)
                acc[mt][nt] = mfma16(af[mt], bfr[nt], acc[mt][nt]);
        __syncthreads();
    }

    const float* bias = (seg == 0) ? bq : (seg == 1) ? bk : bv;
    const float scale = (seg == 0) ? qs : 1.0f;
    __hip_bfloat16* outp = (seg == 0) ? Qb : (seg == 1) ? Kb : Vtb;

    for (int mt = 0; mt < 4; ++mt) {
        for (int nt = 0; nt < 4; ++nt) {
            int nn = nb0 + wc * 64 + nt * 16 + col;
            int h = nn >> 6, d = nn & 63;
            float bn = bias[nn];
            for (int r = 0; r < 4; ++r) {
                int m = tileM + wr * 64 + mt * 16 + quad * 4 + r;
                int b = m >> 12, s = m & 4095;
                float v = (acc[mt][nt][r] + bn) * scale;
                size_t off;
                if (seg < 2) off = (((size_t)(b * 8 + h) * 4096 + s) << 6) + d;
                else         off = (((size_t)(b * 8 + h) * 64 + d) << 12) + s;
                outp[off] = __float2bfloat16(v);
            }
        }
    }
}

// ---------------------------------------------------------------- final GEMM (Wo)
// A = Atb bf16 (gload16-staged); B = Wo fp32 transposed+converted on the fly.
// 64(M) x 128(N) tiles, grid (4, 128) = 512 blocks.
__global__ __launch_bounds__(256, 3) void gemm_out(
    const __hip_bfloat16* __restrict__ A, const float* __restrict__ W,
    const float* __restrict__ bias, float* __restrict__ out)
{
    __shared__ __hip_bfloat16 Abuf[64 * 32];
    __shared__ __hip_bfloat16 Bbuf[128 * 32];
    const int tid = threadIdx.x, w = tid >> 6, lane = tid & 63;
    const int col = lane & 15, quad = lane >> 4;
    const int wr = w >> 1, wc = w & 1;
    const int tileN = blockIdx.x * 128, tileM = blockIdx.y * 64;

    const int kp = tid >> 4, part = tid & 15;
    const int bgrp = (((kp >> 2) ^ (part & 3)) << 2) + (kp & 3);
    uint32_t* B32 = reinterpret_cast<uint32_t*>(Bbuf);

    f32x4 acc[2][4] = {};

    for (int k0 = 0; k0 < 512; k0 += 32) {
        {   // A: 64 rows x 32 k bf16 via async gload16 (row = t>>2, chunk = t&3)
            int row = tid >> 2, c8 = tid & 3;
            gload16(A + (size_t)(tileM + row) * 512 + k0 + c8 * 8,
                    Abuf + (w * 64 + lane) * 8);
        }
        const float* bp0 = W + (size_t)(k0 + 2 * kp) * 512 + tileN + part * 8;
        float4 b00 = *reinterpret_cast<const float4*>(bp0);
        float4 b01 = *reinterpret_cast<const float4*>(bp0 + 4);
        float4 b10 = *reinterpret_cast<const float4*>(bp0 + 512);
        float4 b11 = *reinterpret_cast<const float4*>(bp0 + 516);
        B32[(part * 8 + 0) * 16 + bgrp] = pkbf(b00.x, b10.x);
        B32[(part * 8 + 1) * 16 + bgrp] = pkbf(b00.y, b10.y);
        B32[(part * 8 + 2) * 16 + bgrp] = pkbf(b00.z, b10.z);
        B32[(part * 8 + 3) * 16 + bgrp] = pkbf(b00.w, b10.w);
        B32[(part * 8 + 4) * 16 + bgrp] = pkbf(b01.x, b11.x);
        B32[(part * 8 + 5) * 16 + bgrp] = pkbf(b01.y, b11.y);
        B32[(part * 8 + 6) * 16 + bgrp] = pkbf(b01.z, b11.z);
        B32[(part * 8 + 7) * 16 + bgrp] = pkbf(b01.w, b11.w);
        __syncthreads();

        bf16x8 af[2], bfr[4];
        for (int mt = 0; mt < 2; ++mt)
            af[mt] = *reinterpret_cast<const bf16x8*>(
                Abuf + (wr * 32 + mt * 16 + col) * 32 + quad * 8);
        for (int nt = 0; nt < 4; ++nt) {
            int n = wc * 64 + nt * 16 + col;
            int g = quad ^ ((2 * nt + (col >> 3)) & 3);
            bfr[nt] = *reinterpret_cast<const bf16x8*>(Bbuf + n * 32 + g * 8);
        }
        for (int mt = 0; mt < 2; ++mt)
            for (int nt = 0; nt < 4; ++nt)
                acc[mt][nt] = mfma16(af[mt], bfr[nt], acc[mt][nt]);
        __syncthreads();
    }

    for (int mt = 0; mt < 2; ++mt) {
        for (int nt = 0; nt < 4; ++nt) {
            int n = tileN + wc * 64 + nt * 16 + col;
            float bn = bias[n];
            for (int r = 0; r < 4; ++r) {
                int m = tileM + wr * 32 + mt * 16 + quad * 4 + r;
                out[(size_t)m * 512 + n] = acc[mt][nt][r] + bn;
            }
        }
    }
}

// ---------------------------------------------------------------- flash attention (v4, proven 104us)
// Software-pipelined: iteration kt runs softmax(kt)+PV(kt) (VALU + TB LDS)
// interleaved with QK(kt+1) (MFMA + ds_read) in ONE basic block.
__global__ __launch_bounds__(256) void flash(
    const __hip_bfloat16* __restrict__ Q,   // [B*H, 4096, 64] (pre-scaled)
    const __hip_bfloat16* __restrict__ Kq,  // [B*H, 4096, 64]
    const __hip_bfloat16* __restrict__ Vt,  // [B*H, 64, 4096]
    __hip_bfloat16* __restrict__ attnb)     // [B, 4096, 512]
{
    __shared__ __hip_bfloat16 KT[2][4096];  // 16 KB
    __shared__ __hip_bfloat16 VB[2][4096];  // 16 KB
    __shared__ uint32_t TB[4][1024];        // 16 KB, per-wave P^T staging

    const int bh = blockIdx.y, b = bh >> 3, h = bh & 7;
    const int tid = threadIdx.x, w = tid >> 6, lane = tid & 63;
    const int col = lane & 15, quad = lane >> 4;
    const int q0 = blockIdx.x * 128 + w * 32;
    const int c7 = col & 7;

    const __hip_bfloat16* Qh = Q + (size_t)bh * 4096 * 64;
    const __hip_bfloat16* Kh = Kq + (size_t)bh * 4096 * 64;
    const __hip_bfloat16* Vh = Vt + (size_t)bh * 64 * 4096;

    bf16x8 aq[2][2];
    for (int qh = 0; qh < 2; ++qh)
        for (int ks = 0; ks < 2; ++ks)
            aq[qh][ks] = *reinterpret_cast<const bf16x8*>(
                Qh + (size_t)(q0 + qh * 16 + col) * 64 + ks * 32 + quad * 8);

    const __hip_bfloat16* ksrc[2];
    const __hip_bfloat16* vsrc[2];
    int ldsoff[2];
    for (int i = 0; i < 2; ++i) {
        int c = i * 256 + tid;
        int row = c >> 3, s8 = (c & 7) ^ (row & 7);
        ksrc[i] = Kh + row * 64 + s8 * 8;
        vsrc[i] = Vh + (size_t)row * 4096 + s8 * 8;
        ldsoff[i] = (i * 256 + w * 64) * 8;
    }

    bf16x8 ones;
    for (int j = 0; j < 8; ++j) ones[j] = (__bf16)1.0f;

    f32x4 o[4][2] = {};
    f32x4 accl[2] = {};
    f32x4 sc[2][4][2];

    uint32_t* TBw = &TB[w][0];
    uint2* TBw2 = reinterpret_cast<uint2*>(TBw);

    gload16(ksrc[0], &KT[0][ldsoff[0]]);
    gload16(ksrc[1], &KT[0][ldsoff[1]]);
    gload16(vsrc[0], &VB[0][ldsoff[0]]);
    gload16(vsrc[1], &VB[0][ldsoff[1]]);
    gload16(ksrc[0] + 4096, &KT[1][ldsoff[0]]);
    gload16(ksrc[1] + 4096, &KT[1][ldsoff[1]]);
    __syncthreads();

    for (int kg = 0; kg < 4; ++kg)
        for (int qh = 0; qh < 2; ++qh)
            sc[0][kg][qh] = (f32x4){0.f, 0.f, 0.f, 0.f};
    for (int ks = 0; ks < 2; ++ks)
        for (int kg = 0; kg < 4; ++kg) {
            bf16x8 ak = *reinterpret_cast<const bf16x8*>(
                &KT[0][(kg * 16 + col) * 64 + (((ks * 4 + quad) ^ c7) << 3)]);
            for (int qh = 0; qh < 2; ++qh)
                sc[0][kg][qh] = mfma16(ak, aq[qh][ks], sc[0][kg][qh]);
        }
    __syncthreads();

#define FLASH_BODY(KT_, P_)                                                     \
    {                                                                           \
        const int kt_ = (KT_);                                                  \
        int kk = kt_ + 2; if (kk > 63) kk = 63;                                 \
        gload16(ksrc[0] + (size_t)kk * 4096, &KT[(P_)][ldsoff[0]]);             \
        gload16(ksrc[1] + (size_t)kk * 4096, &KT[(P_)][ldsoff[1]]);             \
        gload16(vsrc[0] + (size_t)(kt_ + 1) * 64, &VB[1 - (P_)][ldsoff[0]]);    \
        gload16(vsrc[1] + (size_t)(kt_ + 1) * 64, &VB[1 - (P_)][ldsoff[1]]);    \
        for (int kg = 0; kg < 4; ++kg)                                          \
            for (int qh = 0; qh < 2; ++qh) {                                    \
                f32x4 v = sc[(P_)][kg][qh];                                     \
                uint2 u;                                                        \
                u.x = pkbf(__builtin_amdgcn_exp2f(v[0]),                        \
                           __builtin_amdgcn_exp2f(v[1]));                       \
                u.y = pkbf(__builtin_amdgcn_exp2f(v[2]),                        \
                           __builtin_amdgcn_exp2f(v[3]));                       \
                TBw2[(qh * 16 + col) * 16 +                                     \
                     (((kg * 2 + (quad >> 1)) ^ c7) << 1) + (quad & 1)] = u;    \
            }                                                                   \
        for (int kg = 0; kg < 4; ++kg)                                          \
            for (int qh = 0; qh < 2; ++qh)                                      \
                sc[1 - (P_)][kg][qh] = (f32x4){0.f, 0.f, 0.f, 0.f};             \
        for (int ks = 0; ks < 2; ++ks)                                          \
            for (int kg = 0; kg < 4; ++kg) {                                    \
                bf16x8 ak = *reinterpret_cast<const bf16x8*>(                   \
                    &KT[1 - (P_)][(kg * 16 + col) * 64 +                        \
                                  (((ks * 4 + quad) ^ c7) << 3)]);              \
                for (int qh = 0; qh < 2; ++qh)                                  \
                    sc[1 - (P_)][kg][qh] =                                      \
                        mfma16(ak, aq[qh][ks], sc[1 - (P_)][kg][qh]);           \
            }                                                                   \
        bf16x8 bp[2][2];                                                        \
        for (int qh = 0; qh < 2; ++qh)                                          \
            for (int ks = 0; ks < 2; ++ks)                                      \
                bp[qh][ks] = *reinterpret_cast<const bf16x8*>(                  \
                    &TBw[(qh * 16 + col) * 32 + (((ks * 4 + quad) ^ c7) << 2)]);\
        for (int ks = 0; ks < 2; ++ks) {                                        \
            for (int dt = 0; dt < 4; ++dt) {                                    \
                bf16x8 av = *reinterpret_cast<const bf16x8*>(                   \
                    &VB[(P_)][(dt * 16 + col) * 64 +                            \
                              (((ks * 4 + quad) ^ c7) << 3)]);                  \
                for (int qh = 0; qh < 2; ++qh)                                  \
                    o[dt][qh] = mfma16(av, bp[qh][ks], o[dt][qh]);              \
            }                                                                   \
            accl[0] = mfma16(ones, bp[0][ks], accl[0]);                         \
            accl[1] = mfma16(ones, bp[1][ks], accl[1]);                         \
        }                                                                       \
        __syncthreads();                                                        \
    }

    FLASH_BODY(0, 0)
    for (int kth = 0; kth < 31; ++kth) {
        FLASH_BODY(2 * kth + 1, 1)
        FLASH_BODY(2 * kth + 2, 0)
    }
    {
        for (int kg = 0; kg < 4; ++kg)
            for (int qh = 0; qh < 2; ++qh) {
                f32x4 v = sc[1][kg][qh];
                uint2 u;
                u.x = pkbf(__builtin_amdgcn_exp2f(v[0]), __builtin_amdgcn_exp2f(v[1]));
                u.y = pkbf(__builtin_amdgcn_exp2f(v[2]), __builtin_amdgcn_exp2f(v[3]));
                TBw2[(qh * 16 + col) * 16 + (((kg * 2 + (quad >> 1)) ^ c7) << 1) + (quad & 1)] = u;
            }
        bf16x8 bp[2][2];
        for (int qh = 0; qh < 2; ++qh)
            for (int ks = 0; ks < 2; ++ks)
                bp[qh][ks] = *reinterpret_cast<const bf16x8*>(
                    &TBw[(qh * 16 + col) * 32 + (((ks * 4 + quad) ^ c7) << 2)]);
        for (int ks = 0; ks < 2; ++ks) {
            for (int dt = 0; dt < 4; ++dt) {
                bf16x8 av = *reinterpret_cast<const bf16x8*>(
                    &VB[1][(dt * 16 + col) * 64 + (((ks * 4 + quad) ^ c7) << 3)]);
                for (int qh = 0; qh < 2; ++qh)
                    o[dt][qh] = mfma16(av, bp[qh][ks], o[dt][qh]);
            }
            accl[0] = mfma16(ones, bp[0][ks], accl[0]);
            accl[1] = mfma16(ones, bp[1][ks], accl[1]);
        }
    }
#undef FLASH_BODY

    for (int qh = 0; qh < 2; ++qh) {
        float inv = 1.0f / accl[qh][0];
        int s = q0 + qh * 16 + col;
        __hip_bfloat16* dst = attnb + ((size_t)b * 4096 + s) * 512 + h * 64 + quad * 4;
        for (int dt = 0; dt < 4; ++dt) {
            union { __hip_bfloat16 hh[4]; ushort4 v4; } pk;
            for (int r = 0; r < 4; ++r)
                pk.hh[r] = __float2bfloat16(o[dt][qh][r] * inv);
            *reinterpret_cast<ushort4*>(dst + dt * 16) = pk.v4;
        }
    }
}

// ---------------------------------------------------------------- launch
extern "C" void kernel_launch(void* const* d_in, const int* in_sizes, int n_in,
                              void* d_out, int out_size, void* d_ws, size_t ws_size,
                              hipStream_t stream) {
    const float* X  = (const float*)d_in[0];
    const float* Wq = (const float*)d_in[1];
    const float* bq = (const float*)d_in[2];
    const float* Wk = (const float*)d_in[3];
    const float* bk = (const float*)d_in[4];
    const float* Wv = (const float*)d_in[5];
    const float* bv = (const float*)d_in[6];
    const float* Wo = (const float*)d_in[7];
    const float* bo = (const float*)d_in[8];
    float* out = (float*)d_out;

    char* ws = (char*)d_ws;
    __hip_bfloat16* Qb  = (__hip_bfloat16*)(ws + ((size_t)10 << 20));
    __hip_bfloat16* Kb  = (__hip_bfloat16*)(ws + ((size_t)18 << 20));
    __hip_bfloat16* Vtb = (__hip_bfloat16*)(ws + ((size_t)26 << 20));
    __hip_bfloat16* Atb = (__hip_bfloat16*)(ws + ((size_t)34 << 20));

    const float qs = 0.125f * 1.4426950408889634f;  // (1/sqrt(64)) * log2(e), folded into Q

    gemm_qkv<<<dim3(12, 64), 256, 0, stream>>>(X, Wq, Wk, Wv, bq, bk, bv, Qb, Kb, Vtb, qs);
    flash<<<dim3(32, 16), 256, 0, stream>>>(Qb, Kb, Vtb, Atb);
    gemm_out<<<dim3(4, 128), 256, 0, stream>>>(Atb, Wo, bo, out);
}